// Round 1
// baseline (1286.304 us; speedup 1.0000x reference)
//
#include <hip/hip_runtime.h>
#include <cstdint>
#include <cstddef>

#define N_PTS 50000
#define H 16
#define CIN 256
#define C 256
#define G 8
#define CPG 32
#define CR 64

__device__ __forceinline__ float lrelu(float x) { return x > 0.f ? x : 0.1f * x; }

// ---------------------------------------------------------------------------
// Kernel 1: QKV = s_feats @ [Wq|Wk|Wv] + bias  -> ws [N][768] (q|k|v)
// Tiled fp32 GEMM: BM=128, BN=64, BK=32, 256 threads, 8x4 per-thread tile.
// ---------------------------------------------------------------------------
#define BM 128
#define BN 64
#define BK 32
#define TM 8
#define TN 4

__global__ __launch_bounds__(256) void qkv_gemm(
    const float* __restrict__ A,
    const float* __restrict__ Wq, const float* __restrict__ bq,
    const float* __restrict__ Wk, const float* __restrict__ bk,
    const float* __restrict__ Wv, const float* __restrict__ bv,
    float* __restrict__ out)
{
    __shared__ float As[BK][BM];
    __shared__ float Bs[BK][BN];
    const int tid = threadIdx.x;
    const int bn = blockIdx.x;   // 0..11  (768 / 64)
    const int bm = blockIdx.y;   // 0..390

    const float* W; const float* bias; int wcol0;
    if (bn < 4)      { W = Wq; bias = bq; wcol0 = bn * 64; }
    else if (bn < 8) { W = Wk; bias = bk; wcol0 = (bn - 4) * 64; }
    else             { W = Wv; bias = bv; wcol0 = (bn - 8) * 64; }

    const int tx = tid & 15;   // 16 cols * TN=4 -> 64
    const int ty = tid >> 4;   // 16 rows * TM=8 -> 128

    float acc[TM][TN] = {};

    for (int k0 = 0; k0 < CIN; k0 += BK) {
        // A tile: 128x32, float4 along k, stored transposed As[k][m]
        #pragma unroll
        for (int i = 0; i < 4; ++i) {
            int l = tid * 4 + i;          // 0..1023
            int m = l >> 3;               // 0..127
            int kk = (l & 7) * 4;
            int gm = bm * BM + m;
            float4 a4 = make_float4(0.f, 0.f, 0.f, 0.f);
            if (gm < N_PTS) a4 = *(const float4*)&A[(size_t)gm * CIN + k0 + kk];
            As[kk + 0][m] = a4.x; As[kk + 1][m] = a4.y;
            As[kk + 2][m] = a4.z; As[kk + 3][m] = a4.w;
        }
        // B tile: 32x64
        #pragma unroll
        for (int i = 0; i < 2; ++i) {
            int l = tid * 2 + i;          // 0..511
            int kk = l >> 4;
            int c4 = (l & 15) * 4;
            float4 b4 = *(const float4*)&W[(size_t)(k0 + kk) * C + wcol0 + c4];
            *(float4*)&Bs[kk][c4] = b4;
        }
        __syncthreads();
        #pragma unroll
        for (int kk = 0; kk < BK; ++kk) {
            float4 b4 = *(const float4*)&Bs[kk][tx * TN];
            float bvv[TN] = {b4.x, b4.y, b4.z, b4.w};
            float4 a0 = *(const float4*)&As[kk][ty * TM];
            float4 a1 = *(const float4*)&As[kk][ty * TM + 4];
            float av[TM] = {a0.x, a0.y, a0.z, a0.w, a1.x, a1.y, a1.z, a1.w};
            #pragma unroll
            for (int im = 0; im < TM; ++im)
                #pragma unroll
                for (int jn = 0; jn < TN; ++jn)
                    acc[im][jn] += av[im] * bvv[jn];
        }
        __syncthreads();
    }

    float4 bb = *(const float4*)&bias[wcol0 + tx * TN];
    #pragma unroll
    for (int im = 0; im < TM; ++im) {
        int gm = bm * BM + ty * TM + im;
        if (gm < N_PTS) {
            float4 o;
            o.x = acc[im][0] + bb.x;
            o.y = acc[im][1] + bb.y;
            o.z = acc[im][2] + bb.z;
            o.w = acc[im][3] + bb.w;
            *(float4*)&out[(size_t)gm * 768 + bn * 64 + tx * TN] = o;
        }
    }
}

// ---------------------------------------------------------------------------
// Kernel 2: fused per-point attention. One block (256 thr) per point;
// thread = channel c. All 16 neighbors batched through Wd2/Wa1 so weights
// are read once per block.
// ---------------------------------------------------------------------------
__global__ __launch_bounds__(256) void attn_kernel(
    const float* __restrict__ qkv,          // [N][768] q|k|v
    const float* __restrict__ q_pts, const float* __restrict__ s_pts,
    const int* __restrict__ nbr,            // [N][H]
    const float* __restrict__ Wd1, const float* __restrict__ bd1,   // [3][64],[64]
    const float* __restrict__ Wd2, const float* __restrict__ bd2,   // [64][256],[256]
    const float* __restrict__ Wa1, const float* __restrict__ ba1,   // [256][32],[32]
    const float* __restrict__ Wa2, const float* __restrict__ ba2,   // [32][32],[32]
    float* __restrict__ out)                // [N][256]
{
    __shared__ float s_rel[H][4];
    __shared__ float s_d1t[CR][H];      // d1 transposed: [r][h]
    __shared__ float s_qk[H][C];
    __shared__ float s_red[H][8][CPG];
    __shared__ float s_a1[H][CPG];
    __shared__ float s_a2[H][CPG];
    __shared__ int   s_idx[H];

    const int n = blockIdx.x;
    const int tid = threadIdx.x;
    const int c = tid;

    if (tid < H) {
        int idx = nbr[(size_t)n * H + tid];
        s_idx[tid] = idx;
        #pragma unroll
        for (int x = 0; x < 3; ++x)
            s_rel[tid][x] = s_pts[(size_t)idx * 3 + x] - q_pts[(size_t)n * 3 + x];
    }
    __syncthreads();

    // d1[h][r] = lrelu(rel[h] @ Wd1[:,r] + bd1[r]), stored transposed [r][h]
    #pragma unroll
    for (int pass = 0; pass < 4; ++pass) {
        int item = pass * 256 + tid;    // = r*16 + h  -> conflict-free writes
        int r = item >> 4;
        int h = item & 15;
        float v = bd1[r] + s_rel[h][0] * Wd1[r]
                         + s_rel[h][1] * Wd1[CR + r]
                         + s_rel[h][2] * Wd1[2 * CR + r];
        s_d1t[r][h] = lrelu(v);
    }
    __syncthreads();

    // geom[h] for all h, plus qk and (v - geom)
    const int idx0 = s_idx[0];
    const float qf = qkv[(size_t)idx0 * 768 + c];

    float geom[H];
    {
        const float b2 = bd2[c];
        #pragma unroll
        for (int h = 0; h < H; ++h) geom[h] = b2;
    }
    for (int r = 0; r < CR; ++r) {
        float w = Wd2[(size_t)r * C + c];          // coalesced, read once/block
        const float4* d4 = (const float4*)&s_d1t[r][0];
        float4 d0 = d4[0], d1 = d4[1], d2 = d4[2], d3 = d4[3];
        geom[0]  += d0.x * w; geom[1]  += d0.y * w;
        geom[2]  += d0.z * w; geom[3]  += d0.w * w;
        geom[4]  += d1.x * w; geom[5]  += d1.y * w;
        geom[6]  += d1.z * w; geom[7]  += d1.w * w;
        geom[8]  += d2.x * w; geom[9]  += d2.y * w;
        geom[10] += d2.z * w; geom[11] += d2.w * w;
        geom[12] += d3.x * w; geom[13] += d3.y * w;
        geom[14] += d3.z * w; geom[15] += d3.w * w;
    }

    float vg[H];
    #pragma unroll
    for (int h = 0; h < H; ++h) {
        int idx = s_idx[h];
        float nk = qkv[(size_t)idx * 768 + 256 + c];
        float nv = qkv[(size_t)idx * 768 + 512 + c];
        vg[h] = nv - geom[h];
        s_qk[h][c] = lrelu(qf - nk - geom[h]);
    }
    __syncthreads();

    // a1 partials: thread (seg, j) accumulates 32-elem segment for all h
    {
        const int j = tid & 31;
        const int seg = tid >> 5;
        float wa1r[32];
        #pragma unroll
        for (int i = 0; i < 32; ++i)
            wa1r[i] = Wa1[(size_t)(seg * 32 + i) * CPG + j];   // once/block total
        #pragma unroll
        for (int h = 0; h < H; ++h) {
            const float4* q4 = (const float4*)&s_qk[h][seg * 32];
            float p = 0.f;
            #pragma unroll
            for (int i4 = 0; i4 < 8; ++i4) {
                float4 q = q4[i4];
                p += q.x * wa1r[i4 * 4 + 0] + q.y * wa1r[i4 * 4 + 1]
                   + q.z * wa1r[i4 * 4 + 2] + q.w * wa1r[i4 * 4 + 3];
            }
            s_red[h][seg][j] = p;
        }
    }
    __syncthreads();

    // reduce partials -> a1 = lrelu(. + ba1)
    #pragma unroll
    for (int pass = 0; pass < 2; ++pass) {
        int h = (tid >> 5) + pass * 8;
        int j = tid & 31;
        float s = ba1[j];
        #pragma unroll
        for (int seg = 0; seg < 8; ++seg) s += s_red[h][seg][j];
        s_a1[h][j] = lrelu(s);
    }
    __syncthreads();

    // a2 = a1 @ Wa2 + ba2
    #pragma unroll
    for (int pass = 0; pass < 2; ++pass) {
        int h = (tid >> 5) + pass * 8;
        int jj = tid & 31;
        float a2 = ba2[jj];
        #pragma unroll
        for (int j = 0; j < 32; ++j)
            a2 += s_a1[h][j] * Wa2[(size_t)j * CPG + jj];
        s_a2[h][jj] = a2;
    }
    __syncthreads();

    // softmax over h (per attention channel j)
    if (tid < CPG) {
        int j = tid;
        float m = -1e30f;
        #pragma unroll
        for (int h = 0; h < H; ++h) m = fmaxf(m, s_a2[h][j]);
        float sum = 0.f;
        #pragma unroll
        for (int h = 0; h < H; ++h) {
            float e = __expf(s_a2[h][j] - m);
            s_a2[h][j] = e;
            sum += e;
        }
        float inv = 1.f / sum;
        #pragma unroll
        for (int h = 0; h < H; ++h) s_a2[h][j] *= inv;
    }
    __syncthreads();

    // out[n][c] = sum_h (v - geom) * attn[h][c/8]
    float o = 0.f;
    const int aj = c >> 3;
    #pragma unroll
    for (int h = 0; h < H; ++h) o += vg[h] * s_a2[h][aj];
    out[(size_t)n * C + c] = o;
}

// ---------------------------------------------------------------------------

extern "C" void kernel_launch(void* const* d_in, const int* in_sizes, int n_in,
                              void* d_out, int out_size, void* d_ws, size_t ws_size,
                              hipStream_t stream) {
    const float* q_pts   = (const float*)d_in[0];
    const float* s_pts   = (const float*)d_in[1];
    const float* s_feats = (const float*)d_in[2];
    const int*   nbr     = (const int*)d_in[3];
    const float* Wq  = (const float*)d_in[4];
    const float* bq  = (const float*)d_in[5];
    const float* Wk  = (const float*)d_in[6];
    const float* bk  = (const float*)d_in[7];
    const float* Wv  = (const float*)d_in[8];
    const float* bv  = (const float*)d_in[9];
    const float* Wd1 = (const float*)d_in[10];
    const float* bd1 = (const float*)d_in[11];
    const float* Wd2 = (const float*)d_in[12];
    const float* bd2 = (const float*)d_in[13];
    const float* Wa1 = (const float*)d_in[14];
    const float* ba1 = (const float*)d_in[15];
    const float* Wa2 = (const float*)d_in[16];
    const float* ba2 = (const float*)d_in[17];

    float* out = (float*)d_out;
    float* qkv = (float*)d_ws;   // [N][768] fp32 = 153.6 MB

    dim3 g1(12, (N_PTS + BM - 1) / BM);
    qkv_gemm<<<g1, 256, 0, stream>>>(s_feats, Wq, bq, Wk, bk, Wv, bv, qkv);

    attn_kernel<<<N_PTS, 256, 0, stream>>>(qkv, q_pts, s_pts, nbr,
                                           Wd1, bd1, Wd2, bd2,
                                           Wa1, ba1, Wa2, ba2, out);
}

// Round 2
// 624.377 us; speedup vs baseline: 2.0601x; 2.0601x over previous
//
#include <hip/hip_runtime.h>
#include <cstdint>
#include <cstddef>

#define N_PTS 50000
#define H 16
#define CIN 256
#define C 256
#define G 8
#define CPG 32
#define CR 64

typedef short bf16x8 __attribute__((ext_vector_type(8)));
typedef float f32x4 __attribute__((ext_vector_type(4)));

__device__ __forceinline__ float lrelu(float x) { return x > 0.f ? x : 0.1f * x; }

// fp32 -> bf16 RNE
__device__ __forceinline__ unsigned short f2bf(float f) {
    unsigned int u = __float_as_uint(f);
    u += 0x7fff + ((u >> 16) & 1);
    return (unsigned short)(u >> 16);
}
__device__ __forceinline__ float bf2f(unsigned short s) {
    return __uint_as_float(((unsigned int)s) << 16);
}

// ---------------------------------------------------------------------------
// Kernel 0: pack Wd2 (64x256), Wa1 (256x32), Wa2 (32x32) into bf16
// B-fragment-major layout for mfma_f32_16x16x32_bf16:
//   frag(kt,nt): lane l holds B[kt*32 + (l>>4)*8 + j][nt*16 + (l&15)], j=0..7
// Region (ushort elems): Wd2 frags [0,16384), Wa1 [16384,24576), Wa2 [24576,25600)
// ---------------------------------------------------------------------------
__global__ __launch_bounds__(256) void prep_frags(
    const float* __restrict__ Wd2, const float* __restrict__ Wa1,
    const float* __restrict__ Wa2, unsigned short* __restrict__ dst)
{
    int t = blockIdx.x * 256 + threadIdx.x;
    if (t >= 3200) return;
    const float* W; int Nc, NT, loc, base;
    if (t < 2048)      { W = Wd2; Nc = 256; NT = 16; loc = t;        base = 0; }
    else if (t < 3072) { W = Wa1; Nc = 32;  NT = 2;  loc = t - 2048; base = 16384; }
    else               { W = Wa2; Nc = 32;  NT = 2;  loc = t - 3072; base = 24576; }
    int f = loc >> 6, lane = loc & 63;
    int kt = f / NT, nt = f - kt * NT;
    int quad = lane >> 4;
    int colc = nt * 16 + (lane & 15);
    int row0 = kt * 32 + (quad << 3);
    unsigned short tmp[8];
    #pragma unroll
    for (int j = 0; j < 8; ++j) tmp[j] = f2bf(W[(size_t)(row0 + j) * Nc + colc]);
    *(bf16x8*)&dst[(size_t)(base + loc * 8)] = *(bf16x8*)tmp;
}

// ---------------------------------------------------------------------------
// Kernel 1: QKV = s_feats @ [Wq|Wk|Wv] + bias -> ws bf16 [N][768] (q|k|v)
// fp32 tiled GEMM (MFMA conversion deferred), bf16 output store.
// ---------------------------------------------------------------------------
#define BM 128
#define BN 64
#define BK 32
#define TM 8
#define TN 4

__global__ __launch_bounds__(256) void qkv_gemm(
    const float* __restrict__ A,
    const float* __restrict__ Wq, const float* __restrict__ bq,
    const float* __restrict__ Wk, const float* __restrict__ bk,
    const float* __restrict__ Wv, const float* __restrict__ bv,
    unsigned short* __restrict__ out)
{
    __shared__ float As[BK][BM];
    __shared__ float Bs[BK][BN];
    const int tid = threadIdx.x;
    const int bn = blockIdx.x;   // 0..11
    const int bm = blockIdx.y;

    const float* W; const float* bias; int wcol0;
    if (bn < 4)      { W = Wq; bias = bq; wcol0 = bn * 64; }
    else if (bn < 8) { W = Wk; bias = bk; wcol0 = (bn - 4) * 64; }
    else             { W = Wv; bias = bv; wcol0 = (bn - 8) * 64; }

    const int tx = tid & 15;
    const int ty = tid >> 4;

    float acc[TM][TN] = {};

    for (int k0 = 0; k0 < CIN; k0 += BK) {
        #pragma unroll
        for (int i = 0; i < 4; ++i) {
            int l = tid * 4 + i;
            int m = l >> 3;
            int kk = (l & 7) * 4;
            int gm = bm * BM + m;
            float4 a4 = make_float4(0.f, 0.f, 0.f, 0.f);
            if (gm < N_PTS) a4 = *(const float4*)&A[(size_t)gm * CIN + k0 + kk];
            As[kk + 0][m] = a4.x; As[kk + 1][m] = a4.y;
            As[kk + 2][m] = a4.z; As[kk + 3][m] = a4.w;
        }
        #pragma unroll
        for (int i = 0; i < 2; ++i) {
            int l = tid * 2 + i;
            int kk = l >> 4;
            int c4 = (l & 15) * 4;
            float4 b4 = *(const float4*)&W[(size_t)(k0 + kk) * C + wcol0 + c4];
            *(float4*)&Bs[kk][c4] = b4;
        }
        __syncthreads();
        #pragma unroll
        for (int kk = 0; kk < BK; ++kk) {
            float4 b4 = *(const float4*)&Bs[kk][tx * TN];
            float bvv[TN] = {b4.x, b4.y, b4.z, b4.w};
            float4 a0 = *(const float4*)&As[kk][ty * TM];
            float4 a1 = *(const float4*)&As[kk][ty * TM + 4];
            float av[TM] = {a0.x, a0.y, a0.z, a0.w, a1.x, a1.y, a1.z, a1.w};
            #pragma unroll
            for (int im = 0; im < TM; ++im)
                #pragma unroll
                for (int jn = 0; jn < TN; ++jn)
                    acc[im][jn] += av[im] * bvv[jn];
        }
        __syncthreads();
    }

    float4 bb = *(const float4*)&bias[wcol0 + tx * TN];
    #pragma unroll
    for (int im = 0; im < TM; ++im) {
        int gm = bm * BM + ty * TM + im;
        if (gm < N_PTS) {
            ushort4 o;
            o.x = f2bf(acc[im][0] + bb.x);
            o.y = f2bf(acc[im][1] + bb.y);
            o.z = f2bf(acc[im][2] + bb.z);
            o.w = f2bf(acc[im][3] + bb.w);
            *(ushort4*)&out[(size_t)gm * 768 + bn * 64 + tx * TN] = o;
        }
    }
}

// ---------------------------------------------------------------------------
// Kernel 2: fused per-point attention with MFMA for geom / a1 / a2.
// 1 block (256 thr = 4 waves) per point.
//   A-layout: lane holds A[m=lane&15][kt*32 + (lane>>4)*8 + j]
//   C/D:      lane holds D[row=(lane>>4)*4+r][col=lane&15]
// ---------------------------------------------------------------------------
#define D1S 72      // s_d1 row stride (bf16): 144 B, 16B-aligned, spreads banks
#define GS 260      // s_geom row stride (fp32): 2-way max
#define QKS 264     // s_qk row stride (bf16): 528 B, 16B-aligned
#define A1S 40      // s_a1 row stride (bf16): 80 B, 16B-aligned
#define A2S 33      // s_a2 row stride (fp32)

__global__ __launch_bounds__(256) void attn_mfma(
    const unsigned short* __restrict__ qkv,   // [N][768] bf16 q|k|v
    const float* __restrict__ q_pts, const float* __restrict__ s_pts,
    const int* __restrict__ nbr,
    const float* __restrict__ Wd1, const float* __restrict__ bd1,
    const float* __restrict__ bd2,
    const unsigned short* __restrict__ frags,
    const float* __restrict__ ba1, const float* __restrict__ ba2,
    float* __restrict__ out)
{
    __shared__ unsigned short s_d1[H * D1S];
    __shared__ float          s_geom[H * GS];
    __shared__ unsigned short s_qk[H * QKS];
    __shared__ unsigned short s_a1[H * A1S];
    __shared__ float          s_a2[H * A2S];
    __shared__ float          s_rel[H][3];
    __shared__ int            s_idx[H];

    const int n = blockIdx.x;
    const int tid = threadIdx.x;
    const int lane = tid & 63;
    const int wave = tid >> 6;
    const int quad = lane >> 4;
    const int col = lane & 15;
    const int m = lane & 15;

    if (tid < H) {
        int idx = nbr[(size_t)n * H + tid];
        s_idx[tid] = idx;
        #pragma unroll
        for (int x = 0; x < 3; ++x)
            s_rel[tid][x] = s_pts[(size_t)idx * 3 + x] - q_pts[(size_t)n * 3 + x];
    }
    __syncthreads();

    // d1[h][r] = lrelu(rel @ Wd1 + bd1) -> bf16 LDS row-major (A-operand)
    #pragma unroll
    for (int p = 0; p < 4; ++p) {
        int item = p * 256 + tid;
        int h = item >> 6, r = item & 63;
        float v = bd1[r] + s_rel[h][0] * Wd1[r]
                         + s_rel[h][1] * Wd1[64 + r]
                         + s_rel[h][2] * Wd1[128 + r];
        s_d1[h * D1S + r] = f2bf(lrelu(v));
    }
    __syncthreads();

    // geom = d1 @ Wd2 (16x64 @ 64x256). Wave w: nt = 4w..4w+3, K-tiles kt=0,1.
    {
        bf16x8 a0 = *(bf16x8*)&s_d1[m * D1S + 0 * 32 + quad * 8];
        bf16x8 a1 = *(bf16x8*)&s_d1[m * D1S + 1 * 32 + quad * 8];
        #pragma unroll
        for (int t = 0; t < 4; ++t) {
            int nt = wave * 4 + t;
            bf16x8 b0 = *(bf16x8*)&frags[((0 * 16 + nt) * 64 + lane) * 8];
            bf16x8 b1 = *(bf16x8*)&frags[((1 * 16 + nt) * 64 + lane) * 8];
            f32x4 acc = {0.f, 0.f, 0.f, 0.f};
            acc = __builtin_amdgcn_mfma_f32_16x16x32_bf16(a0, b0, acc, 0, 0, 0);
            acc = __builtin_amdgcn_mfma_f32_16x16x32_bf16(a1, b1, acc, 0, 0, 0);
            #pragma unroll
            for (int r = 0; r < 4; ++r)
                s_geom[(quad * 4 + r) * GS + nt * 16 + col] = acc[r];
        }
    }
    __syncthreads();

    // Elementwise (thread = channel c): gather nk/nv, form vg and qk=lrelu(...)
    const int c = tid;
    const float qf = bf2f(qkv[(size_t)s_idx[0] * 768 + c]);
    const float b2 = bd2[c];
    float vg[H];
    #pragma unroll
    for (int h = 0; h < H; ++h) {
        int idx = s_idx[h];
        float g  = s_geom[h * GS + c] + b2;
        float nk = bf2f(qkv[(size_t)idx * 768 + 256 + c]);
        float nv = bf2f(qkv[(size_t)idx * 768 + 512 + c]);
        vg[h] = nv - g;
        s_qk[h * QKS + c] = f2bf(lrelu(qf - nk - g));
    }
    __syncthreads();

    // a1 = lrelu(qk @ Wa1 + ba1): 16x256 @ 256x32. Waves 0,1: nt=wave, kt=0..7.
    if (wave < 2) {
        const int nt = wave;
        f32x4 acc = {0.f, 0.f, 0.f, 0.f};
        #pragma unroll
        for (int kt = 0; kt < 8; ++kt) {
            bf16x8 a = *(bf16x8*)&s_qk[m * QKS + kt * 32 + quad * 8];
            bf16x8 b = *(bf16x8*)&frags[16384 + ((kt * 2 + nt) * 64 + lane) * 8];
            acc = __builtin_amdgcn_mfma_f32_16x16x32_bf16(a, b, acc, 0, 0, 0);
        }
        int j = nt * 16 + col;
        float bb = ba1[j];
        #pragma unroll
        for (int r = 0; r < 4; ++r)
            s_a1[(quad * 4 + r) * A1S + j] = f2bf(lrelu(acc[r] + bb));
    }
    __syncthreads();

    // a2 = a1 @ Wa2 + ba2: 16x32 @ 32x32. Waves 0,1: nt=wave, single K-tile.
    if (wave < 2) {
        const int nt = wave;
        bf16x8 a = *(bf16x8*)&s_a1[m * A1S + quad * 8];
        bf16x8 b = *(bf16x8*)&frags[24576 + (nt * 64 + lane) * 8];
        f32x4 acc = {0.f, 0.f, 0.f, 0.f};
        acc = __builtin_amdgcn_mfma_f32_16x16x32_bf16(a, b, acc, 0, 0, 0);
        int j = nt * 16 + col;
        float bb = ba2[j];
        #pragma unroll
        for (int r = 0; r < 4; ++r)
            s_a2[(quad * 4 + r) * A2S + j] = acc[r] + bb;
    }
    __syncthreads();

    // softmax over h per attention channel j
    if (tid < CPG) {
        float mx = -1e30f;
        #pragma unroll
        for (int h = 0; h < H; ++h) mx = fmaxf(mx, s_a2[h * A2S + tid]);
        float sum = 0.f;
        #pragma unroll
        for (int h = 0; h < H; ++h) {
            float e = __expf(s_a2[h * A2S + tid] - mx);
            s_a2[h * A2S + tid] = e;
            sum += e;
        }
        float inv = 1.f / sum;
        #pragma unroll
        for (int h = 0; h < H; ++h) s_a2[h * A2S + tid] *= inv;
    }
    __syncthreads();

    // out[n][c] = sum_h vg[h] * attn[h][c>>3]
    float o = 0.f;
    const int aj = c >> 3;
    #pragma unroll
    for (int h = 0; h < H; ++h) o += vg[h] * s_a2[h * A2S + aj];
    out[(size_t)n * C + c] = o;
}

// ---------------------------------------------------------------------------

extern "C" void kernel_launch(void* const* d_in, const int* in_sizes, int n_in,
                              void* d_out, int out_size, void* d_ws, size_t ws_size,
                              hipStream_t stream) {
    const float* q_pts   = (const float*)d_in[0];
    const float* s_pts   = (const float*)d_in[1];
    const float* s_feats = (const float*)d_in[2];
    const int*   nbr     = (const int*)d_in[3];
    const float* Wq  = (const float*)d_in[4];
    const float* bq  = (const float*)d_in[5];
    const float* Wk  = (const float*)d_in[6];
    const float* bk  = (const float*)d_in[7];
    const float* Wv  = (const float*)d_in[8];
    const float* bv  = (const float*)d_in[9];
    const float* Wd1 = (const float*)d_in[10];
    const float* bd1 = (const float*)d_in[11];
    const float* Wd2 = (const float*)d_in[12];
    const float* bd2 = (const float*)d_in[13];
    const float* Wa1 = (const float*)d_in[14];
    const float* ba1 = (const float*)d_in[15];
    const float* Wa2 = (const float*)d_in[16];
    const float* ba2 = (const float*)d_in[17];

    float* out = (float*)d_out;
    unsigned short* qkvb  = (unsigned short*)d_ws;                    // [N][768] bf16 = 76.8 MB
    unsigned short* frags = (unsigned short*)((char*)d_ws + 76800000); // 50 KB packed weights

    prep_frags<<<13, 256, 0, stream>>>(Wd2, Wa1, Wa2, frags);

    dim3 g1(12, (N_PTS + BM - 1) / BM);
    qkv_gemm<<<g1, 256, 0, stream>>>(s_feats, Wq, bq, Wk, bk, Wv, bv, qkvb);

    attn_mfma<<<N_PTS, 256, 0, stream>>>(qkvb, q_pts, s_pts, nbr,
                                         Wd1, bd1, bd2, frags, ba1, ba2, out);
}

// Round 3
// 426.938 us; speedup vs baseline: 3.0129x; 1.4625x over previous
//
#include <hip/hip_runtime.h>
#include <cstdint>
#include <cstddef>

#define N_PTS 50000
#define H 16
#define CIN 256
#define C 256
#define CPG 32
#define CR 64

typedef short bf16x8 __attribute__((ext_vector_type(8)));
typedef float f32x4 __attribute__((ext_vector_type(4)));

__device__ __forceinline__ unsigned short f2bf(float f) {
    unsigned int u = __float_as_uint(f);
    u += 0x7fff + ((u >> 16) & 1);
    return (unsigned short)(u >> 16);
}
__device__ __forceinline__ float bf2f(unsigned short s) {
    return __uint_as_float(((unsigned int)s) << 16);
}

// ---------------------------------------------------------------------------
// convert s_feats fp32 -> bf16 (row-major [N][256])
// ---------------------------------------------------------------------------
__global__ __launch_bounds__(256) void convert_feats(
    const float* __restrict__ in, unsigned short* __restrict__ outp)
{
    size_t i = ((size_t)blockIdx.x * 256 + threadIdx.x) * 8;   // 6250*256*8 = 12.8M exact
    float4 f0 = *(const float4*)&in[i];
    float4 f1 = *(const float4*)&in[i + 4];
    unsigned short t[8] = {f2bf(f0.x), f2bf(f0.y), f2bf(f0.z), f2bf(f0.w),
                           f2bf(f1.x), f2bf(f1.y), f2bf(f1.z), f2bf(f1.w)};
    *(bf16x8*)&outp[i] = *(bf16x8*)t;
}

// ---------------------------------------------------------------------------
// pack attn weights Wd2(64x256), Wa1(256x32), Wa2(32x32) into bf16 B-frags:
//   frag(kt,nt): lane l holds B[kt*32+(l>>4)*8+j][nt*16+(l&15)], j=0..7
// ushort offsets: Wd2 [0,16384), Wa1 [16384,24576), Wa2 [24576,25600)
// ---------------------------------------------------------------------------
__global__ __launch_bounds__(256) void prep_frags(
    const float* __restrict__ Wd2, const float* __restrict__ Wa1,
    const float* __restrict__ Wa2, unsigned short* __restrict__ dst)
{
    int t = blockIdx.x * 256 + threadIdx.x;
    if (t >= 3200) return;
    const float* W; int Nc, NT, loc, base;
    if (t < 2048)      { W = Wd2; Nc = 256; NT = 16; loc = t;        base = 0; }
    else if (t < 3072) { W = Wa1; Nc = 32;  NT = 2;  loc = t - 2048; base = 16384; }
    else               { W = Wa2; Nc = 32;  NT = 2;  loc = t - 3072; base = 24576; }
    int f = loc >> 6, lane = loc & 63;
    int kt = f / NT, nt = f - kt * NT;
    int colc = nt * 16 + (lane & 15);
    int row0 = kt * 32 + ((lane >> 4) << 3);
    unsigned short tmp[8];
    #pragma unroll
    for (int j = 0; j < 8; ++j) tmp[j] = f2bf(W[(size_t)(row0 + j) * Nc + colc]);
    *(bf16x8*)&dst[(size_t)(base + loc * 8)] = *(bf16x8*)tmp;
}

// ---------------------------------------------------------------------------
// pack [Wq|Wk|Wv] (each 256x256) into B-frags: dst[(kt*48+ntg)*64+lane][8]
// ntg 0..15 -> Wq, 16..31 -> Wk, 32..47 -> Wv
// ---------------------------------------------------------------------------
__global__ __launch_bounds__(256) void prep_gemm_frags(
    const float* __restrict__ Wq, const float* __restrict__ Wk,
    const float* __restrict__ Wv, unsigned short* __restrict__ dst)
{
    int t = blockIdx.x * 256 + threadIdx.x;   // 96*256 = 24576 exact
    int lane = t & 63;
    int f = t >> 6;                           // kt*48 + ntg
    int ntg = f % 48;
    const float* W = ntg < 16 ? Wq : (ntg < 32 ? Wk : Wv);
    int colc = (ntg & 15) * 16 + (lane & 15);
    int row0 = (f / 48) * 32 + ((lane >> 4) << 3);
    unsigned short tmp[8];
    #pragma unroll
    for (int j = 0; j < 8; ++j) tmp[j] = f2bf(W[(size_t)(row0 + j) * 256 + colc]);
    *(bf16x8*)&dst[(size_t)t * 8] = *(bf16x8*)tmp;
}

// ---------------------------------------------------------------------------
// QKV GEMM, bf16 MFMA: [50000x256] @ [256x768] -> bf16 [N][768], kv interleaved:
//   row layout: [0..255]=q, [256+2c]=k[c], [257+2c]=v[c]
// 128x128 tile, 4 waves, wave = 32 rows (2 mt), 8 nt; K-loop kt=0..7.
// ---------------------------------------------------------------------------
__global__ __launch_bounds__(256) void qkv_gemm_mfma(
    const unsigned short* __restrict__ A,       // [N][256] bf16
    const unsigned short* __restrict__ wfrags,
    const float* __restrict__ bq, const float* __restrict__ bk,
    const float* __restrict__ bv, unsigned short* __restrict__ out)
{
    __shared__ unsigned short s_a[128 * 40];    // stride 40 -> 2-way-free banks
    const int tid = threadIdx.x;
    const int lane = tid & 63, wave = tid >> 6;
    const int quad = lane >> 4, col16 = lane & 15;
    const int bx = blockIdx.x, by = blockIdx.y;

    f32x4 acc[2][8] = {};
    const int mrow = tid >> 1, half = tid & 1;
    const int gm = by * 128 + mrow;

    for (int kt = 0; kt < 8; ++kt) {
        bf16x8 a0 = {0,0,0,0,0,0,0,0}, a1 = a0;
        if (gm < N_PTS) {
            const unsigned short* src = &A[(size_t)gm * 256 + kt * 32 + half * 16];
            a0 = *(const bf16x8*)src;
            a1 = *(const bf16x8*)(src + 8);
        }
        __syncthreads();
        *(bf16x8*)&s_a[mrow * 40 + half * 16]     = a0;
        *(bf16x8*)&s_a[mrow * 40 + half * 16 + 8] = a1;
        __syncthreads();
        bf16x8 af0 = *(bf16x8*)&s_a[(wave * 32 + col16) * 40 + quad * 8];
        bf16x8 af1 = *(bf16x8*)&s_a[(wave * 32 + 16 + col16) * 40 + quad * 8];
        #pragma unroll
        for (int nt = 0; nt < 8; ++nt) {
            bf16x8 bf = *(const bf16x8*)&wfrags[(((size_t)kt * 48 + bx * 8 + nt) * 64 + lane) * 8];
            acc[0][nt] = __builtin_amdgcn_mfma_f32_16x16x32_bf16(af0, bf, acc[0][nt], 0, 0, 0);
            acc[1][nt] = __builtin_amdgcn_mfma_f32_16x16x32_bf16(af1, bf, acc[1][nt], 0, 0, 0);
        }
    }

    const int mode = bx >> 1;   // 0=q 1=k 2=v
    const float* bias = mode == 0 ? bq : (mode == 1 ? bk : bv);
    #pragma unroll
    for (int nt = 0; nt < 8; ++nt) {
        int cIn = (bx & 1) * 128 + nt * 16 + col16;
        float bb = bias[cIn];
        int pos = mode == 0 ? cIn : (256 + 2 * cIn + (mode == 2 ? 1 : 0));
        #pragma unroll
        for (int mt = 0; mt < 2; ++mt) {
            #pragma unroll
            for (int r = 0; r < 4; ++r) {
                int row = by * 128 + wave * 32 + mt * 16 + quad * 4 + r;
                if (row < N_PTS)
                    out[(size_t)row * 768 + pos] = f2bf(acc[mt][nt][r] + bb);
            }
        }
    }
}

// ---------------------------------------------------------------------------
// Fused attention: 4 points per block, weight frags hoisted to registers.
// ---------------------------------------------------------------------------
#define D1S 72
#define GS 260
#define QKS 264
#define A1S 40
#define A2S 33

__global__ __launch_bounds__(256) void attn_mfma(
    const unsigned short* __restrict__ qkv,     // [N][768] q | kv-interleaved
    const float* __restrict__ q_pts, const float* __restrict__ s_pts,
    const int* __restrict__ nbr,
    const float* __restrict__ Wd1, const float* __restrict__ bd1,
    const float* __restrict__ bd2,
    const unsigned short* __restrict__ frags,
    const float* __restrict__ ba1, const float* __restrict__ ba2,
    float* __restrict__ out)
{
    __shared__ unsigned short s_d1[H * D1S];
    __shared__ float          s_geom[H * GS];
    __shared__ unsigned short s_qk[H * QKS];
    __shared__ unsigned short s_a1[H * A1S];
    __shared__ float          s_a2[H * A2S];
    __shared__ float          s_rel[4][H][3];
    __shared__ int            s_idx[4][H];

    const int tid = threadIdx.x;
    const int lane = tid & 63, wave = tid >> 6;
    const int quad = lane >> 4, col = lane & 15;
    const int n0 = blockIdx.x * 4;
    const int c = tid;

    if (tid < 64) {
        int pp = tid >> 4, hh = tid & 15;
        int idx = nbr[(size_t)(n0 + pp) * H + hh];
        s_idx[pp][hh] = idx;
        #pragma unroll
        for (int x = 0; x < 3; ++x)
            s_rel[pp][hh][x] = s_pts[(size_t)idx * 3 + x] - q_pts[(size_t)(n0 + pp) * 3 + x];
    }

    // hoisted small weights
    const float w1x = Wd1[lane], w1y = Wd1[64 + lane], w1z = Wd1[128 + lane];
    const float b1 = bd1[lane];
    const float b2 = bd2[c];
    bf16x8 wd2f[2][4];
    #pragma unroll
    for (int t = 0; t < 4; ++t) {
        wd2f[0][t] = *(const bf16x8*)&frags[((size_t)((0 * 16 + wave * 4 + t) * 64 + lane)) * 8];
        wd2f[1][t] = *(const bf16x8*)&frags[((size_t)((1 * 16 + wave * 4 + t) * 64 + lane)) * 8];
    }
    bf16x8 wa1f[8];
    bf16x8 wa2f = {0,0,0,0,0,0,0,0};
    if (wave < 2) {
        #pragma unroll
        for (int kt = 0; kt < 8; ++kt)
            wa1f[kt] = *(const bf16x8*)&frags[16384 + ((size_t)((kt * 2 + wave) * 64 + lane)) * 8];
        wa2f = *(const bf16x8*)&frags[24576 + ((size_t)(wave * 64 + lane)) * 8];
    }
    __syncthreads();

    for (int p = 0; p < 4; ++p) {
        const int n = n0 + p;

        // d1 = lrelu(rel @ Wd1 + bd1), bf16 row-major [h][64]
        #pragma unroll
        for (int pass = 0; pass < 4; ++pass) {
            int h = pass * 4 + wave;
            float v = b1 + s_rel[p][h][0] * w1x + s_rel[p][h][1] * w1y + s_rel[p][h][2] * w1z;
            s_d1[h * D1S + lane] = f2bf(fmaxf(v, 0.1f * v));
        }
        __syncthreads();

        // geom = d1 @ Wd2 (16x64 @ 64x256)
        {
            bf16x8 ga = *(bf16x8*)&s_d1[col * D1S + quad * 8];
            bf16x8 gb = *(bf16x8*)&s_d1[col * D1S + 32 + quad * 8];
            #pragma unroll
            for (int t = 0; t < 4; ++t) {
                f32x4 acc = {0.f, 0.f, 0.f, 0.f};
                acc = __builtin_amdgcn_mfma_f32_16x16x32_bf16(ga, wd2f[0][t], acc, 0, 0, 0);
                acc = __builtin_amdgcn_mfma_f32_16x16x32_bf16(gb, wd2f[1][t], acc, 0, 0, 0);
                int nt = wave * 4 + t;
                #pragma unroll
                for (int rr = 0; rr < 4; ++rr)
                    s_geom[(quad * 4 + rr) * GS + nt * 16 + col] = acc[rr];
            }
        }
        __syncthreads();

        // elementwise: gather kv (one dword = k,v), build vg + qk
        float qf = bf2f(qkv[(size_t)s_idx[p][0] * 768 + c]);
        float vg[H];
        #pragma unroll
        for (int h = 0; h < H; ++h) {
            int idx = s_idx[p][h];
            unsigned int u = *(const unsigned int*)&qkv[(size_t)idx * 768 + 256 + 2 * c];
            float nk = __uint_as_float(u << 16);
            float nv = __uint_as_float(u & 0xffff0000u);
            float g = s_geom[h * GS + c] + b2;
            vg[h] = nv - g;
            float tq = qf - nk - g;
            s_qk[h * QKS + c] = f2bf(fmaxf(tq, 0.1f * tq));
        }
        __syncthreads();

        // a1 = lrelu(qk @ Wa1 + ba1) on waves 0,1
        if (wave < 2) {
            f32x4 acc = {0.f, 0.f, 0.f, 0.f};
            #pragma unroll
            for (int kt = 0; kt < 8; ++kt) {
                bf16x8 a = *(bf16x8*)&s_qk[col * QKS + kt * 32 + quad * 8];
                acc = __builtin_amdgcn_mfma_f32_16x16x32_bf16(a, wa1f[kt], acc, 0, 0, 0);
            }
            int j = wave * 16 + col;
            float bb = ba1[j];
            #pragma unroll
            for (int rr = 0; rr < 4; ++rr) {
                float v = acc[rr] + bb;
                s_a1[(quad * 4 + rr) * A1S + j] = f2bf(fmaxf(v, 0.1f * v));
            }
        }
        __syncthreads();

        // a2 = a1 @ Wa2 + ba2 on waves 0,1
        if (wave < 2) {
            bf16x8 aa = *(bf16x8*)&s_a1[col * A1S + quad * 8];
            f32x4 acc = {0.f, 0.f, 0.f, 0.f};
            acc = __builtin_amdgcn_mfma_f32_16x16x32_bf16(aa, wa2f, acc, 0, 0, 0);
            int j = wave * 16 + col;
            float bb = ba2[j];
            #pragma unroll
            for (int rr = 0; rr < 4; ++rr)
                s_a2[(quad * 4 + rr) * A2S + j] = acc[rr] + bb;
        }
        __syncthreads();

        // softmax over h, wave 0: lane = (half, j)
        if (wave == 0) {
            int j = lane & 31, hb = (lane >> 5) * 8;
            float vals[8];
            float mx = -1e30f;
            #pragma unroll
            for (int i = 0; i < 8; ++i) {
                vals[i] = s_a2[(hb + i) * A2S + j];
                mx = fmaxf(mx, vals[i]);
            }
            mx = fmaxf(mx, __shfl_xor(mx, 32));
            float sum = 0.f;
            #pragma unroll
            for (int i = 0; i < 8; ++i) { vals[i] = __expf(vals[i] - mx); sum += vals[i]; }
            sum += __shfl_xor(sum, 32);
            float inv = 1.f / sum;
            #pragma unroll
            for (int i = 0; i < 8; ++i) s_a2[(hb + i) * A2S + j] = vals[i] * inv;
        }
        __syncthreads();

        // out[n][c] = sum_h vg[h] * attn[h][c>>3]
        float o = 0.f;
        const int aj = c >> 3;
        #pragma unroll
        for (int h = 0; h < H; ++h) o += vg[h] * s_a2[h * A2S + aj];
        out[(size_t)n * C + c] = o;
        // no trailing barrier needed: next stage writing s_a2 is 4 barriers away
    }
}

// ---------------------------------------------------------------------------

extern "C" void kernel_launch(void* const* d_in, const int* in_sizes, int n_in,
                              void* d_out, int out_size, void* d_ws, size_t ws_size,
                              hipStream_t stream) {
    const float* q_pts   = (const float*)d_in[0];
    const float* s_pts   = (const float*)d_in[1];
    const float* s_feats = (const float*)d_in[2];
    const int*   nbr     = (const int*)d_in[3];
    const float* Wq  = (const float*)d_in[4];
    const float* bq  = (const float*)d_in[5];
    const float* Wk  = (const float*)d_in[6];
    const float* bk  = (const float*)d_in[7];
    const float* Wv  = (const float*)d_in[8];
    const float* bv  = (const float*)d_in[9];
    const float* Wd1 = (const float*)d_in[10];
    const float* bd1 = (const float*)d_in[11];
    const float* Wd2 = (const float*)d_in[12];
    const float* bd2 = (const float*)d_in[13];
    const float* Wa1 = (const float*)d_in[14];
    const float* ba1 = (const float*)d_in[15];
    const float* Wa2 = (const float*)d_in[16];
    const float* ba2 = (const float*)d_in[17];

    float* out = (float*)d_out;
    char* ws = (char*)d_ws;
    unsigned short* A_bf16    = (unsigned short*)(ws);                 // 25.6 MB
    unsigned short* qkvb      = (unsigned short*)(ws + 25600000);      // 76.8 MB
    unsigned short* attnFrags = (unsigned short*)(ws + 102400000);     // 51.2 KB
    unsigned short* gemmFrags = (unsigned short*)(ws + 102451200);     // 384 KB

    convert_feats<<<6250, 256, 0, stream>>>(s_feats, A_bf16);
    prep_frags<<<13, 256, 0, stream>>>(Wd2, Wa1, Wa2, attnFrags);
    prep_gemm_frags<<<96, 256, 0, stream>>>(Wq, Wk, Wv, gemmFrags);

    dim3 g1(6, (N_PTS + 127) / 128);
    qkv_gemm_mfma<<<g1, 256, 0, stream>>>(A_bf16, gemmFrags, bq, bk, bv, qkvb);

    attn_mfma<<<(N_PTS / 4), 256, 0, stream>>>(qkvb, q_pts, s_pts, nbr,
                                               Wd1, bd1, bd2, attnFrags,
                                               ba1, ba2, out);
}